// Round 9
// baseline (256.825 us; speedup 1.0000x reference)
//
#include <hip/hip_runtime.h>

// CP-rank-32: out[i,j,k] = sum_r W0[i,r]*W1[j,r]*W2[k,r]; out 256x256x1024 fp32 (268MB).
// Ladder: R3 NT/LDS 80 -> R7 NT/f2/6w 78 -> R8 plain/f2/6w 73. Plain>NT at high occ.
// Mixed-traffic roofline ~50us (268MB W + ~40MB R @ 6.3TB/s); residual = latency.
// R9: float1/thread -> w[32] scalar = 32 VGPR, launch_bounds(256,8) -> 8 waves/SIMD
//     (fill-kernel-like); XCD-chunked block swizzle so C reads stay XCD-local.
// FMA order r=0..31 sequential per element, c = round(W0*W1) — bit-exact (absmax 0.0).

constexpr int I_DIM  = 256;
constexpr int J_DIM  = 256;
constexpr int K_DIM  = 1024;
constexpr int RNK    = 32;
constexpr int JSEG   = 64;             // j's per block
constexpr int KQ     = 4;              // k-quarters
constexpr int KCHUNK = K_DIM / KQ;     // 256 k's per block (256 thr * 1 float)
constexpr int NXCD   = 8;

// W2 (1024x32) -> W2T (32x1024): w loads coalesced in k.
__global__ void transpose_w2(const float* __restrict__ W2, float* __restrict__ W2T) {
    int idx = blockIdx.x * 256 + threadIdx.x;   // 0 .. 32767
    int r = idx >> 10;
    int k = idx & (K_DIM - 1);
    W2T[r * K_DIM + k] = W2[k * RNK + r];
}

// C[i][j][r] = W0[i,r] * W1[j,r]   (8 MB)
__global__ void precompute_c(const float* __restrict__ W0, const float* __restrict__ W1,
                             float* __restrict__ C) {
    int idx = blockIdx.x * 256 + threadIdx.x;
    int r = idx & 31;
    int j = (idx >> 5) & 255;
    int i = idx >> 13;
    C[idx] = W0[i * RNK + r] * W1[j * RNK + r];
}

// Block: (i, jseg, kq) via XCD-chunked swizzle. Thread: ONE k. w[32] scalar in regs.
// Hot loop per jj: 32 uniform c loads + 32 FMA chain + 1 plain dword store.
__global__ __launch_bounds__(256, 8) void cp_recon_f1(const float* __restrict__ C,
                                                      const float* __restrict__ W2T,
                                                      float* __restrict__ out) {
    // grid = 4096 = 8 XCDs * 512. Dispatch round-robins XCD = b % 8; give each XCD
    // a contiguous work range so each XCD touches only its i-slice of C (bijective).
    const int b    = blockIdx.x;
    const int w_id = (b & (NXCD - 1)) * (4096 / NXCD) + (b >> 3);
    const int i    = w_id >> 4;
    const int jseg = (w_id >> 2) & 3;          // J_DIM/JSEG = 4
    const int kq   = w_id & (KQ - 1);
    const int jbase = jseg * JSEG;
    const int k     = kq * KCHUNK + threadIdx.x;

    // Rank-32 W2T slice for this thread's k: 32 floats = 32 VGPRs, loaded once (L2-hit).
    float w[RNK];
#pragma unroll
    for (int r = 0; r < RNK; ++r)
        w[r] = W2T[r * K_DIM + k];

    const float* __restrict__ crow = C + (size_t)(i * J_DIM + jbase) * RNK;
    float* __restrict__ obase = out + (size_t)(i * J_DIM + jbase) * K_DIM + k;

#pragma unroll 2
    for (int jj = 0; jj < JSEG; ++jj) {
        const float* __restrict__ cj = crow + jj * RNK;  // block-uniform address
        float acc = 0.f;
#pragma unroll
        for (int r = 0; r < RNK; ++r)
            acc = fmaf(cj[r], w[r], acc);
        obase[(size_t)jj * K_DIM] = acc;                 // plain coalesced dword store
    }
}

// ---- Fallback (no ws): direct W2 reads, LDS-c, JT=8 ----
constexpr int JT = 8;
__global__ __launch_bounds__(256, 4) void cp_recon_d(const float* __restrict__ W0,
                                                     const float* __restrict__ W1,
                                                     const float* __restrict__ W2,
                                                     float* __restrict__ out) {
    __shared__ __align__(16) float c[JT][RNK];
    const int i     = blockIdx.x >> 5;
    const int jbase = (blockIdx.x & 31) * JT;
    const int tid   = threadIdx.x;

    if (tid < JT * RNK) {
        int jj = tid >> 5;
        int r  = tid & 31;
        c[jj][r] = W0[i * RNK + r] * W1[(jbase + jj) * RNK + r];
    }
    __syncthreads();

    const int k = tid * 4;
    float4 acc[JT];
#pragma unroll
    for (int jj = 0; jj < JT; ++jj) acc[jj] = make_float4(0.f, 0.f, 0.f, 0.f);

    for (int rc = 0; rc < RNK; rc += 4) {
        float4 row[4];
#pragma unroll
        for (int q = 0; q < 4; ++q)
            row[q] = *reinterpret_cast<const float4*>(&W2[(k + q) * RNK + rc]);
#pragma unroll
        for (int jj = 0; jj < JT; ++jj) {
            float4 c4 = *reinterpret_cast<const float4*>(&c[jj][rc]);
            acc[jj].x = fmaf(c4.x, row[0].x, fmaf(c4.y, row[0].y, fmaf(c4.z, row[0].z, fmaf(c4.w, row[0].w, acc[jj].x))));
            acc[jj].y = fmaf(c4.x, row[1].x, fmaf(c4.y, row[1].y, fmaf(c4.z, row[1].z, fmaf(c4.w, row[1].w, acc[jj].y))));
            acc[jj].z = fmaf(c4.x, row[2].x, fmaf(c4.y, row[2].y, fmaf(c4.z, row[2].z, fmaf(c4.w, row[2].w, acc[jj].z))));
            acc[jj].w = fmaf(c4.x, row[3].x, fmaf(c4.y, row[3].y, fmaf(c4.z, row[3].z, fmaf(c4.w, row[3].w, acc[jj].w))));
        }
    }
#pragma unroll
    for (int jj = 0; jj < JT; ++jj) {
        int o = (i * J_DIM + jbase + jj) * K_DIM + k;
        *reinterpret_cast<float4*>(&out[o]) = acc[jj];
    }
}

extern "C" void kernel_launch(void* const* d_in, const int* in_sizes, int n_in,
                              void* d_out, int out_size, void* d_ws, size_t ws_size,
                              hipStream_t stream) {
    const float* W0 = (const float*)d_in[0];
    const float* W1 = (const float*)d_in[1];
    const float* W2 = (const float*)d_in[2];
    float* out = (float*)d_out;

    const size_t w2t_bytes = (size_t)RNK * K_DIM * sizeof(float);          // 128 KB
    const size_t c_bytes   = (size_t)I_DIM * J_DIM * RNK * sizeof(float);  // 8 MB

    if (ws_size >= w2t_bytes + c_bytes) {
        float* W2T  = (float*)d_ws;
        float* Cbuf = (float*)((char*)d_ws + w2t_bytes);
        transpose_w2<<<(RNK * K_DIM) / 256, 256, 0, stream>>>(W2, W2T);
        precompute_c<<<(I_DIM * J_DIM * RNK) / 256, 256, 0, stream>>>(W0, W1, Cbuf);
        const int grid = I_DIM * (J_DIM / JSEG) * KQ;  // 4096
        cp_recon_f1<<<grid, 256, 0, stream>>>(Cbuf, W2T, out);
    } else {
        cp_recon_d<<<I_DIM * (J_DIM / JT), 256, 0, stream>>>(W0, W1, W2, out);
    }
}

// Round 10
// 77.854 us; speedup vs baseline: 3.2988x; 3.2988x over previous
//
#include <hip/hip_runtime.h>

// CP-rank-32: out[i,j,k] = sum_r W0[i,r]*W1[j,r]*W2[k,r]; out 256x256x1024 fp32 (268MB).
// Ladder: R3 80 / R7 78 / R8 73 (plain f2, 6 waves/SIMD, s_load c) / R9 277 (3-var
// change: f1+KQ4+swizzle -> FETCH 328MB, K$/write-path pathology. Reverted.)
// R10 = R8 with ONE change: c-row staged in LDS (8KB, one coalesced block read),
// hot loop reads c via 8x ds_read_b128 broadcast instead of 32 s_load floats.
// Mechanism: kills scalar-K$ thrash (6-7 blocks/CU x 8KB c-rows >> K$).
// FMA order r=0..31 sequential per element — bit-exact across all rounds (absmax 0.0).

constexpr int I_DIM  = 256;
constexpr int J_DIM  = 256;
constexpr int K_DIM  = 1024;
constexpr int RNK    = 32;
constexpr int JSEG   = 64;             // j's per block
constexpr int KSPLIT = 2;              // k-halves
constexpr int KCHUNK = K_DIM / KSPLIT; // 512 k's per block (256 thr * float2)

typedef float f32x2 __attribute__((ext_vector_type(2)));

// W2 (1024x32) -> W2T (32x1024): w loads coalesced in k.
__global__ void transpose_w2(const float* __restrict__ W2, float* __restrict__ W2T) {
    int idx = blockIdx.x * 256 + threadIdx.x;   // 0 .. 32767
    int r = idx >> 10;
    int k = idx & (K_DIM - 1);
    W2T[r * K_DIM + k] = W2[k * RNK + r];
}

// C[i][j][r] = W0[i,r] * W1[j,r]   (8 MB)
__global__ void precompute_c(const float* __restrict__ W0, const float* __restrict__ W1,
                             float* __restrict__ C) {
    int idx = blockIdx.x * 256 + threadIdx.x;
    int r = idx & 31;
    int j = (idx >> 5) & 255;
    int i = idx >> 13;
    C[idx] = W0[i * RNK + r] * W1[j * RNK + r];
}

// Block: (i, jseg, khalf). Thread: one k-float2. w[32] float2 in regs (64 VGPR),
// c-row in LDS (8 KB). Hot loop per jj: 8 ds_read_b128 + 64 FMA + 1 dwordx2 store.
__global__ __launch_bounds__(256, 4) void cp_recon_f2l(const float* __restrict__ C,
                                                       const float* __restrict__ W2T,
                                                       float* __restrict__ out) {
    __shared__ __align__(16) float4 cl[JSEG * RNK / 4];   // 512 float4 = 8 KB
    const int b     = blockIdx.x;
    const int khalf = b & (KSPLIT - 1);
    const int jseg  = (b >> 1) & 3;             // J_DIM/JSEG = 4
    const int i     = b >> 3;
    const int jbase = jseg * JSEG;
    const int k     = khalf * KCHUNK + threadIdx.x * 2;

    // Stage c-row (64 j x 32 r) into LDS: 2 coalesced float4 loads per thread.
    {
        const float4* __restrict__ c4 = reinterpret_cast<const float4*>(
            C + (size_t)(i * J_DIM + jbase) * RNK);
        cl[threadIdx.x]       = c4[threadIdx.x];
        cl[threadIdx.x + 256] = c4[threadIdx.x + 256];
    }

    // Rank-32 W2T slice for this thread's 2 k's: 32 float2 = 64 VGPRs, loaded once.
    float2 w[RNK];
#pragma unroll
    for (int r = 0; r < RNK; ++r)
        w[r] = *reinterpret_cast<const float2*>(&W2T[r * K_DIM + k]);

    __syncthreads();

    float* __restrict__ obase = out + (size_t)(i * J_DIM + jbase) * K_DIM + k;

#pragma unroll 2
    for (int jj = 0; jj < JSEG; ++jj) {
        float ax = 0.f, ay = 0.f;
#pragma unroll
        for (int q = 0; q < 8; ++q) {
            float4 cv = cl[jj * 8 + q];          // same addr all lanes: broadcast, no conflict
            ax = fmaf(cv.x, w[q * 4 + 0].x, ax);
            ay = fmaf(cv.x, w[q * 4 + 0].y, ay);
            ax = fmaf(cv.y, w[q * 4 + 1].x, ax);
            ay = fmaf(cv.y, w[q * 4 + 1].y, ay);
            ax = fmaf(cv.z, w[q * 4 + 2].x, ax);
            ay = fmaf(cv.z, w[q * 4 + 2].y, ay);
            ax = fmaf(cv.w, w[q * 4 + 3].x, ax);
            ay = fmaf(cv.w, w[q * 4 + 3].y, ay);
        }
        f32x2 t = { ax, ay };
        *reinterpret_cast<f32x2*>(obase + (size_t)jj * K_DIM) = t;  // plain dwordx2 store
    }
}

// ---- Fallback (no ws): direct W2 reads, LDS-c, JT=8 ----
constexpr int JT = 8;
__global__ __launch_bounds__(256, 4) void cp_recon_d(const float* __restrict__ W0,
                                                     const float* __restrict__ W1,
                                                     const float* __restrict__ W2,
                                                     float* __restrict__ out) {
    __shared__ __align__(16) float c[JT][RNK];
    const int i     = blockIdx.x >> 5;
    const int jbase = (blockIdx.x & 31) * JT;
    const int tid   = threadIdx.x;

    if (tid < JT * RNK) {
        int jj = tid >> 5;
        int r  = tid & 31;
        c[jj][r] = W0[i * RNK + r] * W1[(jbase + jj) * RNK + r];
    }
    __syncthreads();

    const int k = tid * 4;
    float4 acc[JT];
#pragma unroll
    for (int jj = 0; jj < JT; ++jj) acc[jj] = make_float4(0.f, 0.f, 0.f, 0.f);

    for (int rc = 0; rc < RNK; rc += 4) {
        float4 row[4];
#pragma unroll
        for (int q = 0; q < 4; ++q)
            row[q] = *reinterpret_cast<const float4*>(&W2[(k + q) * RNK + rc]);
#pragma unroll
        for (int jj = 0; jj < JT; ++jj) {
            float4 c4 = *reinterpret_cast<const float4*>(&c[jj][rc]);
            acc[jj].x = fmaf(c4.x, row[0].x, fmaf(c4.y, row[0].y, fmaf(c4.z, row[0].z, fmaf(c4.w, row[0].w, acc[jj].x))));
            acc[jj].y = fmaf(c4.x, row[1].x, fmaf(c4.y, row[1].y, fmaf(c4.z, row[1].z, fmaf(c4.w, row[1].w, acc[jj].y))));
            acc[jj].z = fmaf(c4.x, row[2].x, fmaf(c4.y, row[2].y, fmaf(c4.z, row[2].z, fmaf(c4.w, row[2].w, acc[jj].z))));
            acc[jj].w = fmaf(c4.x, row[3].x, fmaf(c4.y, row[3].y, fmaf(c4.z, row[3].z, fmaf(c4.w, row[3].w, acc[jj].w))));
        }
    }
#pragma unroll
    for (int jj = 0; jj < JT; ++jj) {
        int o = (i * J_DIM + jbase + jj) * K_DIM + k;
        *reinterpret_cast<float4*>(&out[o]) = acc[jj];
    }
}

extern "C" void kernel_launch(void* const* d_in, const int* in_sizes, int n_in,
                              void* d_out, int out_size, void* d_ws, size_t ws_size,
                              hipStream_t stream) {
    const float* W0 = (const float*)d_in[0];
    const float* W1 = (const float*)d_in[1];
    const float* W2 = (const float*)d_in[2];
    float* out = (float*)d_out;

    const size_t w2t_bytes = (size_t)RNK * K_DIM * sizeof(float);          // 128 KB
    const size_t c_bytes   = (size_t)I_DIM * J_DIM * RNK * sizeof(float);  // 8 MB

    if (ws_size >= w2t_bytes + c_bytes) {
        float* W2T  = (float*)d_ws;
        float* Cbuf = (float*)((char*)d_ws + w2t_bytes);
        transpose_w2<<<(RNK * K_DIM) / 256, 256, 0, stream>>>(W2, W2T);
        precompute_c<<<(I_DIM * J_DIM * RNK) / 256, 256, 0, stream>>>(W0, W1, Cbuf);
        const int grid = I_DIM * (J_DIM / JSEG) * KSPLIT;  // 2048
        cp_recon_f2l<<<grid, 256, 0, stream>>>(Cbuf, W2T, out);
    } else {
        cp_recon_d<<<I_DIM * (J_DIM / JT), 256, 0, stream>>>(W0, W1, W2, out);
    }
}

// Round 11
// 73.640 us; speedup vs baseline: 3.4876x; 1.0572x over previous
//
#include <hip/hip_runtime.h>

// CP-rank-32: out[i,j,k] = sum_r W0[i,r]*W1[j,r]*W2[k,r]; out 256x256x1024 fp32 (268MB).
// Ladder: R3 80(NT,LDS) / R7 78(NT,f2) / R8 73(plain,f2,s_load c,LB4) / R10 78(LDS-c).
// R9 (f1+swizzle+LB8) = 277: FETCH blowup — do not combine those again.
// Floor: max(write 39us @6.9TB/s, VALU 27us) ~ 40-45us. R8 residual ~25us = per-jj
// lgkm-wait serialization at only 4 waves/SIMD.
// R11 = R8 with ONE change: LB(256,4) -> LB(256,6). w[32]f2=64 VGPR + ~16 overhead
// fits the 85-VGPR budget; 6 waves/SIMD to hide the s_load->FMA->store chain.
// FMA order r=0..31 sequential per element — bit-exact across all rounds (absmax 0.0).

constexpr int I_DIM  = 256;
constexpr int J_DIM  = 256;
constexpr int K_DIM  = 1024;
constexpr int RNK    = 32;
constexpr int JSEG   = 64;             // j's per block
constexpr int KSPLIT = 2;              // k-halves
constexpr int KCHUNK = K_DIM / KSPLIT; // 512 k's per block (256 thr * float2)

typedef float f32x2 __attribute__((ext_vector_type(2)));

// W2 (1024x32) -> W2T (32x1024): w loads coalesced in k.
__global__ void transpose_w2(const float* __restrict__ W2, float* __restrict__ W2T) {
    int idx = blockIdx.x * 256 + threadIdx.x;   // 0 .. 32767
    int r = idx >> 10;
    int k = idx & (K_DIM - 1);
    W2T[r * K_DIM + k] = W2[k * RNK + r];
}

// C[i][j][r] = W0[i,r] * W1[j,r]   (8 MB)
__global__ void precompute_c(const float* __restrict__ W0, const float* __restrict__ W1,
                             float* __restrict__ C) {
    int idx = blockIdx.x * 256 + threadIdx.x;
    int r = idx & 31;
    int j = (idx >> 5) & 255;
    int i = idx >> 13;
    C[idx] = W0[i * RNK + r] * W1[j * RNK + r];
}

// Block: (i, jseg, khalf). Thread: one k-float2. w[32] float2 in regs, c via SMEM.
// Hot loop per jj: 32 uniform c s_loads + 64 FMA + 1 plain dwordx2 store.
__global__ __launch_bounds__(256, 6) void cp_recon_f2(const float* __restrict__ C,
                                                      const float* __restrict__ W2T,
                                                      float* __restrict__ out) {
    const int b     = blockIdx.x;
    const int khalf = b & (KSPLIT - 1);
    const int jseg  = (b >> 1) & 3;             // J_DIM/JSEG = 4
    const int i     = b >> 3;
    const int jbase = jseg * JSEG;
    const int k     = khalf * KCHUNK + threadIdx.x * 2;

    // Rank-32 W2T slice for this thread's 2 k's: 32 float2 = 64 VGPRs, loaded once.
    float2 w[RNK];
#pragma unroll
    for (int r = 0; r < RNK; ++r)
        w[r] = *reinterpret_cast<const float2*>(&W2T[r * K_DIM + k]);

    const float* __restrict__ crow = C + (size_t)(i * J_DIM + jbase) * RNK;
    float* __restrict__ obase = out + (size_t)(i * J_DIM + jbase) * K_DIM + k;

#pragma unroll 2
    for (int jj = 0; jj < JSEG; ++jj) {
        const float* __restrict__ cj = crow + jj * RNK;  // wave-uniform -> s_load
        float ax = 0.f, ay = 0.f;
#pragma unroll
        for (int r = 0; r < RNK; ++r) {
            float s = cj[r];
            ax = fmaf(s, w[r].x, ax);
            ay = fmaf(s, w[r].y, ay);
        }
        f32x2 t = { ax, ay };
        *reinterpret_cast<f32x2*>(obase + (size_t)jj * K_DIM) = t;  // plain dwordx2 store
    }
}

// ---- Fallback (no ws): direct W2 reads, LDS-c, JT=8 ----
constexpr int JT = 8;
__global__ __launch_bounds__(256, 4) void cp_recon_d(const float* __restrict__ W0,
                                                     const float* __restrict__ W1,
                                                     const float* __restrict__ W2,
                                                     float* __restrict__ out) {
    __shared__ __align__(16) float c[JT][RNK];
    const int i     = blockIdx.x >> 5;
    const int jbase = (blockIdx.x & 31) * JT;
    const int tid   = threadIdx.x;

    if (tid < JT * RNK) {
        int jj = tid >> 5;
        int r  = tid & 31;
        c[jj][r] = W0[i * RNK + r] * W1[(jbase + jj) * RNK + r];
    }
    __syncthreads();

    const int k = tid * 4;
    float4 acc[JT];
#pragma unroll
    for (int jj = 0; jj < JT; ++jj) acc[jj] = make_float4(0.f, 0.f, 0.f, 0.f);

    for (int rc = 0; rc < RNK; rc += 4) {
        float4 row[4];
#pragma unroll
        for (int q = 0; q < 4; ++q)
            row[q] = *reinterpret_cast<const float4*>(&W2[(k + q) * RNK + rc]);
#pragma unroll
        for (int jj = 0; jj < JT; ++jj) {
            float4 c4 = *reinterpret_cast<const float4*>(&c[jj][rc]);
            acc[jj].x = fmaf(c4.x, row[0].x, fmaf(c4.y, row[0].y, fmaf(c4.z, row[0].z, fmaf(c4.w, row[0].w, acc[jj].x))));
            acc[jj].y = fmaf(c4.x, row[1].x, fmaf(c4.y, row[1].y, fmaf(c4.z, row[1].z, fmaf(c4.w, row[1].w, acc[jj].y))));
            acc[jj].z = fmaf(c4.x, row[2].x, fmaf(c4.y, row[2].y, fmaf(c4.z, row[2].z, fmaf(c4.w, row[2].w, acc[jj].z))));
            acc[jj].w = fmaf(c4.x, row[3].x, fmaf(c4.y, row[3].y, fmaf(c4.z, row[3].z, fmaf(c4.w, row[3].w, acc[jj].w))));
        }
    }
#pragma unroll
    for (int jj = 0; jj < JT; ++jj) {
        int o = (i * J_DIM + jbase + jj) * K_DIM + k;
        *reinterpret_cast<float4*>(&out[o]) = acc[jj];
    }
}

extern "C" void kernel_launch(void* const* d_in, const int* in_sizes, int n_in,
                              void* d_out, int out_size, void* d_ws, size_t ws_size,
                              hipStream_t stream) {
    const float* W0 = (const float*)d_in[0];
    const float* W1 = (const float*)d_in[1];
    const float* W2 = (const float*)d_in[2];
    float* out = (float*)d_out;

    const size_t w2t_bytes = (size_t)RNK * K_DIM * sizeof(float);          // 128 KB
    const size_t c_bytes   = (size_t)I_DIM * J_DIM * RNK * sizeof(float);  // 8 MB

    if (ws_size >= w2t_bytes + c_bytes) {
        float* W2T  = (float*)d_ws;
        float* Cbuf = (float*)((char*)d_ws + w2t_bytes);
        transpose_w2<<<(RNK * K_DIM) / 256, 256, 0, stream>>>(W2, W2T);
        precompute_c<<<(I_DIM * J_DIM * RNK) / 256, 256, 0, stream>>>(W0, W1, Cbuf);
        const int grid = I_DIM * (J_DIM / JSEG) * KSPLIT;  // 2048
        cp_recon_f2<<<grid, 256, 0, stream>>>(Cbuf, W2T, out);
    } else {
        cp_recon_d<<<I_DIM * (J_DIM / JT), 256, 0, stream>>>(W0, W1, W2, out);
    }
}

// Round 12
// 67.518 us; speedup vs baseline: 3.8038x; 1.0907x over previous
//
#include <hip/hip_runtime.h>

// CP-rank-32: out[i,j,k] = sum_r W0[i,r]*W1[j,r]*W2[k,r]; out 256x256x1024 fp32 (268MB).
// Ladder: R3 80 / R7 78 / R8 73 (plain f2, s_load c) / R10 78 (LDS-c) / R11 73.6 (LB6
// flat -> latency NOT the residual). R5 114 explained: per-jj vector loads share vmcnt
// with stores ->每jj wait drains store queue. c must stay on s_load (lgkm) path.
// R12: DRAM-write-locality test. Block=(i, 32 j's), thread=k-float4 -> per jj one FULL
// 4KB contiguous j-row store; block sweeps 128KB sequentially (fill-kernel-like).
// w[32] float4 = 128 VGPR, LB(256,3). Plain dwordx4 stores. s_load c.
// FMA order r=0..31 sequential per element — bit-exact across all rounds (absmax 0.0).

constexpr int I_DIM  = 256;
constexpr int J_DIM  = 256;
constexpr int K_DIM  = 1024;
constexpr int RNK    = 32;
constexpr int JSEG   = 32;             // j's per block (128 KB sequential region)

typedef float f32x4 __attribute__((ext_vector_type(4)));

// W2 (1024x32) -> W2T (32x1024): w loads coalesced in k.
__global__ void transpose_w2(const float* __restrict__ W2, float* __restrict__ W2T) {
    int idx = blockIdx.x * 256 + threadIdx.x;   // 0 .. 32767
    int r = idx >> 10;
    int k = idx & (K_DIM - 1);
    W2T[r * K_DIM + k] = W2[k * RNK + r];
}

// C[i][j][r] = W0[i,r] * W1[j,r]   (8 MB)
__global__ void precompute_c(const float* __restrict__ W0, const float* __restrict__ W1,
                             float* __restrict__ C) {
    int idx = blockIdx.x * 256 + threadIdx.x;
    int r = idx & 31;
    int j = (idx >> 5) & 255;
    int i = idx >> 13;
    C[idx] = W0[i * RNK + r] * W1[j * RNK + r];
}

// Block: (i, jseg). Thread: one k-float4 (1024 k covered). Per jj: 32 s_load c +
// 128 FMA + ONE 4KB-contiguous block store. Sequential 128KB sweep per block.
__global__ __launch_bounds__(256, 3) void cp_recon_f4s(const float* __restrict__ C,
                                                       const float* __restrict__ W2T,
                                                       float* __restrict__ out) {
    const int b     = blockIdx.x;
    const int jseg  = b & 7;                    // J_DIM/JSEG = 8
    const int i     = b >> 3;
    const int jbase = jseg * JSEG;
    const int k     = threadIdx.x * 4;

    // Rank-32 W2T slice for this thread's 4 k's: 32 float4 = 128 VGPRs, loaded once.
    float4 w[RNK];
#pragma unroll
    for (int r = 0; r < RNK; ++r)
        w[r] = *reinterpret_cast<const float4*>(&W2T[r * K_DIM + k]);

    const float* __restrict__ crow = C + (size_t)(i * J_DIM + jbase) * RNK;
    float* __restrict__ obase = out + (size_t)(i * J_DIM + jbase) * K_DIM + k;

#pragma unroll 2
    for (int jj = 0; jj < JSEG; ++jj) {
        const float* __restrict__ cj = crow + jj * RNK;  // block-uniform -> s_load (lgkm)
        float4 acc = make_float4(0.f, 0.f, 0.f, 0.f);
#pragma unroll
        for (int r = 0; r < RNK; ++r) {
            float s = cj[r];
            acc.x = fmaf(s, w[r].x, acc.x);
            acc.y = fmaf(s, w[r].y, acc.y);
            acc.z = fmaf(s, w[r].z, acc.z);
            acc.w = fmaf(s, w[r].w, acc.w);
        }
        f32x4 t = { acc.x, acc.y, acc.z, acc.w };
        *reinterpret_cast<f32x4*>(obase + (size_t)jj * K_DIM) = t;  // plain dwordx4
    }
}

// ---- Fallback (no ws): direct W2 reads, LDS-c, JT=8 ----
constexpr int JT = 8;
__global__ __launch_bounds__(256, 4) void cp_recon_d(const float* __restrict__ W0,
                                                     const float* __restrict__ W1,
                                                     const float* __restrict__ W2,
                                                     float* __restrict__ out) {
    __shared__ __align__(16) float c[JT][RNK];
    const int i     = blockIdx.x >> 5;
    const int jbase = (blockIdx.x & 31) * JT;
    const int tid   = threadIdx.x;

    if (tid < JT * RNK) {
        int jj = tid >> 5;
        int r  = tid & 31;
        c[jj][r] = W0[i * RNK + r] * W1[(jbase + jj) * RNK + r];
    }
    __syncthreads();

    const int k = tid * 4;
    float4 acc[JT];
#pragma unroll
    for (int jj = 0; jj < JT; ++jj) acc[jj] = make_float4(0.f, 0.f, 0.f, 0.f);

    for (int rc = 0; rc < RNK; rc += 4) {
        float4 row[4];
#pragma unroll
        for (int q = 0; q < 4; ++q)
            row[q] = *reinterpret_cast<const float4*>(&W2[(k + q) * RNK + rc]);
#pragma unroll
        for (int jj = 0; jj < JT; ++jj) {
            float4 c4 = *reinterpret_cast<const float4*>(&c[jj][rc]);
            acc[jj].x = fmaf(c4.x, row[0].x, fmaf(c4.y, row[0].y, fmaf(c4.z, row[0].z, fmaf(c4.w, row[0].w, acc[jj].x))));
            acc[jj].y = fmaf(c4.x, row[1].x, fmaf(c4.y, row[1].y, fmaf(c4.z, row[1].z, fmaf(c4.w, row[1].w, acc[jj].y))));
            acc[jj].z = fmaf(c4.x, row[2].x, fmaf(c4.y, row[2].y, fmaf(c4.z, row[2].z, fmaf(c4.w, row[2].w, acc[jj].z))));
            acc[jj].w = fmaf(c4.x, row[3].x, fmaf(c4.y, row[3].y, fmaf(c4.z, row[3].z, fmaf(c4.w, row[3].w, acc[jj].w))));
        }
    }
#pragma unroll
    for (int jj = 0; jj < JT; ++jj) {
        int o = (i * J_DIM + jbase + jj) * K_DIM + k;
        *reinterpret_cast<float4*>(&out[o]) = acc[jj];
    }
}

extern "C" void kernel_launch(void* const* d_in, const int* in_sizes, int n_in,
                              void* d_out, int out_size, void* d_ws, size_t ws_size,
                              hipStream_t stream) {
    const float* W0 = (const float*)d_in[0];
    const float* W1 = (const float*)d_in[1];
    const float* W2 = (const float*)d_in[2];
    float* out = (float*)d_out;

    const size_t w2t_bytes = (size_t)RNK * K_DIM * sizeof(float);          // 128 KB
    const size_t c_bytes   = (size_t)I_DIM * J_DIM * RNK * sizeof(float);  // 8 MB

    if (ws_size >= w2t_bytes + c_bytes) {
        float* W2T  = (float*)d_ws;
        float* Cbuf = (float*)((char*)d_ws + w2t_bytes);
        transpose_w2<<<(RNK * K_DIM) / 256, 256, 0, stream>>>(W2, W2T);
        precompute_c<<<(I_DIM * J_DIM * RNK) / 256, 256, 0, stream>>>(W0, W1, Cbuf);
        const int grid = I_DIM * (J_DIM / JSEG);  // 2048
        cp_recon_f4s<<<grid, 256, 0, stream>>>(Cbuf, W2T, out);
    } else {
        cp_recon_d<<<I_DIM * (J_DIM / JT), 256, 0, stream>>>(W0, W1, W2, out);
    }
}

// Round 13
// 66.383 us; speedup vs baseline: 3.8689x; 1.0171x over previous
//
#include <hip/hip_runtime.h>

// CP-rank-32: out[i,j,k] = sum_r W0[i,r]*W1[j,r]*W2[k,r]; out 256x256x1024 fp32 (268MB).
// Ladder: R8 73 (f2,s_load,plain) / R11 73.6 (LB6 flat) / R12 67.5 (f4 sequential
// 4KB-row sweeps -> DRAM write locality confirmed).
// Floors: write 39us @6.9TB/s; VALU 27us scalar v_fma. 27+39=66 ~= measured 62-64
// -> VALU issue and store stream are ADDING, not overlapping.
// R13 = R12 with ONE change: k-packed v_pk_fma_f32 (2 FMA/inst) via f32x2
// __builtin_elementwise_fma -> VALU busy/issue halves (27->14us), stores interleave.
// Per-element chain still r=0..31 sequential fused -> bit-exact (absmax 0.0).

constexpr int I_DIM  = 256;
constexpr int J_DIM  = 256;
constexpr int K_DIM  = 1024;
constexpr int RNK    = 32;
constexpr int JSEG   = 32;             // j's per block (128 KB sequential region)

typedef float f32x2 __attribute__((ext_vector_type(2)));
typedef float f32x4 __attribute__((ext_vector_type(4)));

#if defined(__has_builtin)
#  if __has_builtin(__builtin_elementwise_fma)
#    define PK_FMA(a, b, c) __builtin_elementwise_fma((a), (b), (c))
#  endif
#endif

__device__ __forceinline__ f32x2 fma2(f32x2 a, f32x2 b, f32x2 c) {
#ifdef PK_FMA
    return PK_FMA(a, b, c);
#else
    f32x2 r;
    r.x = fmaf(a.x, b.x, c.x);
    r.y = fmaf(a.y, b.y, c.y);
    return r;
#endif
}

// W2 (1024x32) -> W2T (32x1024): w loads coalesced in k.
__global__ void transpose_w2(const float* __restrict__ W2, float* __restrict__ W2T) {
    int idx = blockIdx.x * 256 + threadIdx.x;   // 0 .. 32767
    int r = idx >> 10;
    int k = idx & (K_DIM - 1);
    W2T[r * K_DIM + k] = W2[k * RNK + r];
}

// C[i][j][r] = W0[i,r] * W1[j,r]   (8 MB)
__global__ void precompute_c(const float* __restrict__ W0, const float* __restrict__ W1,
                             float* __restrict__ C) {
    int idx = blockIdx.x * 256 + threadIdx.x;
    int r = idx & 31;
    int j = (idx >> 5) & 255;
    int i = idx >> 13;
    C[idx] = W0[i * RNK + r] * W1[j * RNK + r];
}

// Block: (i, jseg). Thread: one k-float4. Per jj: 32 s_load c + 64 v_pk_fma_f32 +
// ONE 4KB-contiguous row store (block sweeps 128KB sequentially).
__global__ __launch_bounds__(256, 3) void cp_recon_f4p(const float* __restrict__ C,
                                                       const float* __restrict__ W2T,
                                                       float* __restrict__ out) {
    const int b     = blockIdx.x;
    const int jseg  = b & 7;                    // J_DIM/JSEG = 8
    const int i     = b >> 3;
    const int jbase = jseg * JSEG;
    const int k     = threadIdx.x * 4;

    // Rank-32 W2T slice, split into lo/hi f32x2 pairs: 128 VGPRs, loaded once.
    f32x2 wlo[RNK], whi[RNK];
#pragma unroll
    for (int r = 0; r < RNK; ++r) {
        f32x4 t = *reinterpret_cast<const f32x4*>(&W2T[r * K_DIM + k]);
        wlo[r] = t.lo;
        whi[r] = t.hi;
    }

    const float* __restrict__ crow = C + (size_t)(i * J_DIM + jbase) * RNK;
    float* __restrict__ obase = out + (size_t)(i * J_DIM + jbase) * K_DIM + k;

#pragma unroll 2
    for (int jj = 0; jj < JSEG; ++jj) {
        const float* __restrict__ cj = crow + jj * RNK;  // block-uniform -> s_load (lgkm)
        f32x2 a0 = {0.f, 0.f}, a1 = {0.f, 0.f};
#pragma unroll
        for (int r = 0; r < RNK; ++r) {
            float s = cj[r];
            f32x2 sv = {s, s};
            a0 = fma2(sv, wlo[r], a0);
            a1 = fma2(sv, whi[r], a1);
        }
        f32x4 t;
        t.lo = a0;
        t.hi = a1;
        *reinterpret_cast<f32x4*>(obase + (size_t)jj * K_DIM) = t;  // plain dwordx4
    }
}

// ---- Fallback (no ws): direct W2 reads, LDS-c, JT=8 ----
constexpr int JT = 8;
__global__ __launch_bounds__(256, 4) void cp_recon_d(const float* __restrict__ W0,
                                                     const float* __restrict__ W1,
                                                     const float* __restrict__ W2,
                                                     float* __restrict__ out) {
    __shared__ __align__(16) float c[JT][RNK];
    const int i     = blockIdx.x >> 5;
    const int jbase = (blockIdx.x & 31) * JT;
    const int tid   = threadIdx.x;

    if (tid < JT * RNK) {
        int jj = tid >> 5;
        int r  = tid & 31;
        c[jj][r] = W0[i * RNK + r] * W1[(jbase + jj) * RNK + r];
    }
    __syncthreads();

    const int k = tid * 4;
    float4 acc[JT];
#pragma unroll
    for (int jj = 0; jj < JT; ++jj) acc[jj] = make_float4(0.f, 0.f, 0.f, 0.f);

    for (int rc = 0; rc < RNK; rc += 4) {
        float4 row[4];
#pragma unroll
        for (int q = 0; q < 4; ++q)
            row[q] = *reinterpret_cast<const float4*>(&W2[(k + q) * RNK + rc]);
#pragma unroll
        for (int jj = 0; jj < JT; ++jj) {
            float4 c4 = *reinterpret_cast<const float4*>(&c[jj][rc]);
            acc[jj].x = fmaf(c4.x, row[0].x, fmaf(c4.y, row[0].y, fmaf(c4.z, row[0].z, fmaf(c4.w, row[0].w, acc[jj].x))));
            acc[jj].y = fmaf(c4.x, row[1].x, fmaf(c4.y, row[1].y, fmaf(c4.z, row[1].z, fmaf(c4.w, row[1].w, acc[jj].y))));
            acc[jj].z = fmaf(c4.x, row[2].x, fmaf(c4.y, row[2].y, fmaf(c4.z, row[2].z, fmaf(c4.w, row[2].w, acc[jj].z))));
            acc[jj].w = fmaf(c4.x, row[3].x, fmaf(c4.y, row[3].y, fmaf(c4.z, row[3].z, fmaf(c4.w, row[3].w, acc[jj].w))));
        }
    }
#pragma unroll
    for (int jj = 0; jj < JT; ++jj) {
        int o = (i * J_DIM + jbase + jj) * K_DIM + k;
        *reinterpret_cast<float4*>(&out[o]) = acc[jj];
    }
}

extern "C" void kernel_launch(void* const* d_in, const int* in_sizes, int n_in,
                              void* d_out, int out_size, void* d_ws, size_t ws_size,
                              hipStream_t stream) {
    const float* W0 = (const float*)d_in[0];
    const float* W1 = (const float*)d_in[1];
    const float* W2 = (const float*)d_in[2];
    float* out = (float*)d_out;

    const size_t w2t_bytes = (size_t)RNK * K_DIM * sizeof(float);          // 128 KB
    const size_t c_bytes   = (size_t)I_DIM * J_DIM * RNK * sizeof(float);  // 8 MB

    if (ws_size >= w2t_bytes + c_bytes) {
        float* W2T  = (float*)d_ws;
        float* Cbuf = (float*)((char*)d_ws + w2t_bytes);
        transpose_w2<<<(RNK * K_DIM) / 256, 256, 0, stream>>>(W2, W2T);
        precompute_c<<<(I_DIM * J_DIM * RNK) / 256, 256, 0, stream>>>(W0, W1, Cbuf);
        const int grid = I_DIM * (J_DIM / JSEG);  // 2048
        cp_recon_f4p<<<grid, 256, 0, stream>>>(Cbuf, W2T, out);
    } else {
        cp_recon_d<<<I_DIM * (J_DIM / JT), 256, 0, stream>>>(W0, W1, W2, out);
    }
}